// Round 10
// baseline (158.806 us; speedup 1.0000x reference)
//
#include <hip/hip_runtime.h>
#include <hip/hip_bf16.h>

// TT-Linear: out = (((x~(B,64,64) x C0) x C1) x C2) x C3 + bias
// Pipeline: transpose_cast2 -> stage2(512t) -> gemm_pipe (gemm1) -> gemm2_8ph
// + XCD-aware block swizzle on both GEMMs (256 blocks = 32/XCD, same-bn).

typedef _Float16 h2 __attribute__((ext_vector_type(2)));
typedef _Float16 h4 __attribute__((ext_vector_type(4)));
typedef _Float16 h8 __attribute__((ext_vector_type(8)));
typedef float f32x4 __attribute__((ext_vector_type(4)));

#define BATCH 8192

__device__ __forceinline__ void gld_lds16(const void* g, void* l) {
  __builtin_amdgcn_global_load_lds(
      (__attribute__((address_space(1))) void*)(g),
      (__attribute__((address_space(3))) void*)(l), 16, 0, 0);
}

// Both weight transposes in one launch. grid (32,16,2).
__global__ __launch_bounds__(256) void transpose_cast2(
    const float* __restrict__ c1, _Float16* __restrict__ W1t,
    const float* __restrict__ c2, _Float16* __restrict__ W2t) {
  __shared__ float t[64][65];
  const int which = blockIdx.z;
  const float* src = which ? c2 : c1;
  _Float16* dst = which ? W2t : W1t;
  const int K = which ? 1024 : 2048, U = which ? 2048 : 1024;
  const int k0 = (which ? blockIdx.y : blockIdx.x) * 64;
  const int u0 = (which ? blockIdx.x : blockIdx.y) * 64;
  const int tx = threadIdx.x & 63, ty = threadIdx.x >> 6;
  for (int i = ty; i < 64; i += 4) {
    const int k = k0 + i;
    const int sr = which ? k : ((k & 31) * 64 + (k >> 5));
    t[i][tx] = src[(size_t)sr * U + u0 + tx];
  }
  __syncthreads();
  for (int i = ty; i < 64; i += 4) {
    dst[(size_t)(u0 + i) * K + k0 + tx] = (_Float16)t[tx][i];
  }
}

// stage2 (512t): s1[b, d*32+r] = sum_c x[b,c*64+d]*C0[c*32+r], fp16 out.
// 4 rows/block, 512 threads (8 waves -> 32 waves/CU with 4 blocks/CU),
// thread tile 4d x 4r, 20 VALU/c-iter, conflict-free broadcast LDS reads.
__global__ __launch_bounds__(512) void stage2(const float* __restrict__ x,
                                              const float* __restrict__ c0,
                                              _Float16* __restrict__ s1) {
  __shared__ _Float16 xh[4 * 4096];  // 32 KB
  __shared__ float c0l[2048];        // 8 KB
  const int b0 = blockIdx.x * 4;
  const int tid = threadIdx.x;

  {
    const float4* xg = (const float4*)(x + (size_t)b0 * 4096);
#pragma unroll
    for (int k = 0; k < 8; ++k) {
      float4 v = xg[tid + 512 * k];
      h4 w = {(_Float16)v.x, (_Float16)v.y, (_Float16)v.z, (_Float16)v.w};
      ((h4*)xh)[tid + 512 * k] = w;
    }
    ((float4*)c0l)[tid] = ((const float4*)c0)[tid];
  }
  __syncthreads();

  const int row = tid >> 7, t7 = tid & 127;
  const int d0 = (t7 >> 3) * 4;  // 16 d-groups (broadcast reads)
  const int r0 = (t7 & 7) * 4;   // 8 r-groups (contiguous stores)
  const _Float16* xrow = xh + row * 4096;

  float acc[4][4] = {};
  for (int c = 0; c < 64; ++c) {
    h4 xv = *(const h4*)&xrow[c * 64 + d0];
    f32x4 wv = *(const f32x4*)&c0l[c * 32 + r0];
#pragma unroll
    for (int i = 0; i < 4; ++i) {
      const float xf = (float)xv[i];
#pragma unroll
      for (int j = 0; j < 4; ++j) acc[i][j] += xf * wv[j];
    }
  }

  _Float16* s1row = s1 + (size_t)(b0 + row) * 2048;
#pragma unroll
  for (int i = 0; i < 4; ++i) {
    h4 o = {(_Float16)acc[i][0], (_Float16)acc[i][1], (_Float16)acc[i][2],
            (_Float16)acc[i][3]};
    *(h4*)&s1row[(d0 + i) * 32 + r0] = o;
  }
}

// gemm1 (r5 structure): BM=128, BN=256, BK=64, 512 threads, 3 LDS buffers,
// counted vmcnt(6), 2-phase fine interleave. 1-D grid + XCD swizzle.
template <int K, int CN, int NBM>
__global__ __launch_bounds__(512, 2) void gemm_pipe(
    const _Float16* __restrict__ A, const _Float16* __restrict__ Bt,
    _Float16* __restrict__ C) {
  __shared__ __align__(16) char lds[3 * 49152];
  constexpr int NT = K / 64;
  const int lin = blockIdx.x;
  const int swz = (lin & 7) * 32 + (lin >> 3);  // 256 blocks, 32/XCD
  const int bm = swz % NBM, bn = swz / NBM;
  const int tid = threadIdx.x;
  const int w = tid >> 6, lane = tid & 63;
  const int lr = lane & 15, kh = lane >> 4;
  const int wmo = (w >> 2) << 6, wno = (w & 3) << 6;

  f32x4 acc[4][4] = {};

  const int sr = tid >> 3;
  const int sc = ((tid & 7) ^ (sr & 7)) << 4;
  const char* gA = (const char*)(A + (size_t)(bm * 128 + sr) * K) + sc;
  const char* gB = (const char*)(Bt + (size_t)(bn * 256 + sr) * K) + sc;
  const size_t rk = (size_t)K * 128;
  char* lw = lds + (w << 10);

  auto STAGE_A = [&](int t) {
    char* b_ = lw + (t % 3) * 49152;
    const char* ga = gA + (size_t)t * 128;
    gld_lds16(ga, b_);
    gld_lds16(ga + rk, b_ + 8192);
    gld_lds16(gB + (size_t)t * 128, b_ + 16384);
  };
  auto STAGE_B = [&](int t) {
    char* b_ = lw + (t % 3) * 49152;
    const char* gb = gB + (size_t)t * 128;
    gld_lds16(gb + rk, b_ + 24576);
    gld_lds16(gb + 2 * rk, b_ + 32768);
    gld_lds16(gb + 3 * rk, b_ + 40960);
  };

  auto KTILE = [&](int t, bool last) {
    if (last)
      asm volatile("s_waitcnt vmcnt(0)" ::: "memory");
    else
      asm volatile("s_waitcnt vmcnt(6)" ::: "memory");
    __builtin_amdgcn_s_barrier();
    __builtin_amdgcn_sched_barrier(0);
    const char* bufA = lds + (t % 3) * 49152;
    const char* bufB = bufA + 16384;
    h8 af[2][4], bf[2][4];
#pragma unroll
    for (int kk = 0; kk < 2; ++kk) {
#pragma unroll
      for (int m = 0; m < 4; ++m) {
        const int R = wmo + m * 16 + lr;
        af[kk][m] = *(const h8*)(bufA + R * 128 +
                                 ((((kk << 2) + kh) ^ (R & 7)) << 4));
      }
#pragma unroll
      for (int n = 0; n < 2; ++n) {
        const int R = wno + n * 16 + lr;
        bf[kk][n] = *(const h8*)(bufB + R * 128 +
                                 ((((kk << 2) + kh) ^ (R & 7)) << 4));
      }
    }
    if (t + 2 < NT) STAGE_A(t + 2);
    asm volatile("s_waitcnt lgkmcnt(0)" ::: "memory");
    __builtin_amdgcn_sched_barrier(0);
    __builtin_amdgcn_s_setprio(1);
#pragma unroll
    for (int kk = 0; kk < 2; ++kk)
#pragma unroll
      for (int m = 0; m < 4; ++m)
#pragma unroll
        for (int n = 0; n < 2; ++n)
          acc[m][n] = __builtin_amdgcn_mfma_f32_16x16x32_f16(
              af[kk][m], bf[kk][n], acc[m][n], 0, 0, 0);
    __builtin_amdgcn_s_setprio(0);
    __builtin_amdgcn_s_barrier();
    __builtin_amdgcn_sched_barrier(0);
#pragma unroll
    for (int kk = 0; kk < 2; ++kk)
#pragma unroll
      for (int n = 2; n < 4; ++n) {
        const int R = wno + n * 16 + lr;
        bf[kk][n] = *(const h8*)(bufB + R * 128 +
                                 ((((kk << 2) + kh) ^ (R & 7)) << 4));
      }
    if (t + 2 < NT) STAGE_B(t + 2);
    asm volatile("s_waitcnt lgkmcnt(0)" ::: "memory");
    __builtin_amdgcn_sched_barrier(0);
    __builtin_amdgcn_s_setprio(1);
#pragma unroll
    for (int kk = 0; kk < 2; ++kk)
#pragma unroll
      for (int m = 0; m < 4; ++m)
#pragma unroll
        for (int n = 2; n < 4; ++n)
          acc[m][n] = __builtin_amdgcn_mfma_f32_16x16x32_f16(
              af[kk][m], bf[kk][n], acc[m][n], 0, 0, 0);
    __builtin_amdgcn_s_setprio(0);
  };

  STAGE_A(0); STAGE_B(0);
  STAGE_A(1); STAGE_B(1);
  for (int t = 0; t < NT - 1; ++t) KTILE(t, false);
  KTILE(NT - 1, true);

#pragma unroll
  for (int m = 0; m < 4; ++m) {
    const int r0 = bm * 128 + wmo + m * 16 + kh * 4;
#pragma unroll
    for (int n = 0; n < 4; ++n) {
      const int c0 = bn * 256 + wno + n * 16 + lr;
#pragma unroll
      for (int q = 0; q < 4; ++q)
        C[(size_t)(r0 + q) * CN + c0] = (_Float16)acc[m][n][q];
    }
  }
}

// gemm2, 8-phase (r8/r9 structure) + swapped epilogue + XCD swizzle.
template <int K, int NBM>
__global__ __launch_bounds__(512, 2) void gemm2_8ph(
    const _Float16* __restrict__ A, const _Float16* __restrict__ Bt,
    const float* __restrict__ c3, const float* __restrict__ bias,
    float* __restrict__ out) {
  __shared__ __align__(16) char lds[131072];
  constexpr int NT = K / 64;
  const int lin = blockIdx.x;
  const int swz = (lin & 7) * 32 + (lin >> 3);  // 256 blocks, 32/XCD
  const int bm = swz % NBM, bn = swz / NBM;
  const int tid = threadIdx.x;
  const int w = tid >> 6, lane = tid & 63;
  const int lr = lane & 15, kh = lane >> 4;
  const int l7 = lr & 7;

  f32x4 acc[8][4] = {};

  const int sr = tid >> 3;
  const int sc = ((tid & 7) ^ (sr & 7)) << 4;
  const size_t rowK = (size_t)K * 2;
  const char* gA = (const char*)A + (size_t)(bm * 256 + sr) * rowK + sc;
  const char* gB = (const char*)Bt + (size_t)(bn * 256 + sr) * rowK + sc;
  char* lw = lds + (w << 10);

  auto STAGE = [&](int kind, int t) {
    char* d = lw + kind * 32768 + (t & 1) * 16384;
    const char* g = (kind < 2 ? gA : gB) + (size_t)(kind & 1) * 128 * rowK +
                    (size_t)t * 128;
    gld_lds16(g, d);
    gld_lds16(g + 64 * rowK, d + 8192);
  };

  const char* bufA0 = lds + (w >> 2) * 32768;
  const char* bufB0 = lds + 65536 + ((w & 3) >> 1) * 32768;
  const int bcol = (w & 1) * 64;

  h8 af[2][4], bflo[2][2], bfhi[2][2];

  STAGE(0, 0); STAGE(1, 0); STAGE(2, 0); STAGE(3, 0);
  STAGE(2, 1); STAGE(0, 1); STAGE(1, 1);
  asm volatile("s_waitcnt vmcnt(6)" ::: "memory");
  __builtin_amdgcn_sched_barrier(0);
  __builtin_amdgcn_s_barrier();

  for (int t = 0; t < NT; ++t) {
    const char* bA = bufA0 + (t & 1) * 16384;
    const char* bB = bufB0 + (t & 1) * 16384;
    // ---------------- P1: (rh0, nlo) ----------------
#pragma unroll
    for (int kk = 0; kk < 2; ++kk) {
#pragma unroll
      for (int m = 0; m < 4; ++m)
        af[kk][m] = *(const h8*)(bA + (m * 16 + lr) * 128 +
                                 ((((kk << 2) + kh) ^ l7) << 4));
#pragma unroll
      for (int n = 0; n < 2; ++n)
        bflo[kk][n] = *(const h8*)(bB + (bcol + n * 16 + lr) * 128 +
                                   ((((kk << 2) + kh) ^ l7) << 4));
    }
    if (t + 1 < NT) STAGE(3, t + 1);
    __builtin_amdgcn_sched_barrier(0);
    __builtin_amdgcn_s_barrier();
    asm volatile("s_waitcnt lgkmcnt(0)" ::: "memory");
    __builtin_amdgcn_sched_barrier(0);
    __builtin_amdgcn_s_setprio(1);
#pragma unroll
    for (int kk = 0; kk < 2; ++kk)
#pragma unroll
      for (int m = 0; m < 4; ++m)
#pragma unroll
        for (int n = 0; n < 2; ++n)
          acc[m][n] = __builtin_amdgcn_mfma_f32_16x16x32_f16(
              af[kk][m], bflo[kk][n], acc[m][n], 0, 0, 0);
    __builtin_amdgcn_s_setprio(0);
    __builtin_amdgcn_s_barrier();
    // ---------------- P2: (rh0, nhi) ----------------
#pragma unroll
    for (int kk = 0; kk < 2; ++kk)
#pragma unroll
      for (int n = 0; n < 2; ++n)
        bfhi[kk][n] = *(const h8*)(bB + (bcol + 32 + n * 16 + lr) * 128 +
                                   ((((kk << 2) + kh) ^ l7) << 4));
    if (t + 2 < NT) STAGE(2, t + 2);
    __builtin_amdgcn_sched_barrier(0);
    __builtin_amdgcn_s_barrier();
    asm volatile("s_waitcnt lgkmcnt(0)" ::: "memory");
    __builtin_amdgcn_sched_barrier(0);
    __builtin_amdgcn_s_setprio(1);
#pragma unroll
    for (int kk = 0; kk < 2; ++kk)
#pragma unroll
      for (int m = 0; m < 4; ++m)
#pragma unroll
        for (int n = 0; n < 2; ++n)
          acc[m][2 + n] = __builtin_amdgcn_mfma_f32_16x16x32_f16(
              af[kk][m], bfhi[kk][n], acc[m][2 + n], 0, 0, 0);
    __builtin_amdgcn_s_setprio(0);
    __builtin_amdgcn_s_barrier();
    // ---------------- P3: (rh1, nlo) ----------------
#pragma unroll
    for (int kk = 0; kk < 2; ++kk)
#pragma unroll
      for (int m = 0; m < 4; ++m)
        af[kk][m] = *(const h8*)(bA + (64 + m * 16 + lr) * 128 +
                                 ((((kk << 2) + kh) ^ l7) << 4));
    __builtin_amdgcn_sched_barrier(0);
    __builtin_amdgcn_s_barrier();
    asm volatile("s_waitcnt lgkmcnt(0)" ::: "memory");
    __builtin_amdgcn_sched_barrier(0);
    __builtin_amdgcn_s_setprio(1);
#pragma unroll
    for (int kk = 0; kk < 2; ++kk)
#pragma unroll
      for (int m = 0; m < 4; ++m)
#pragma unroll
        for (int n = 0; n < 2; ++n)
          acc[4 + m][n] = __builtin_amdgcn_mfma_f32_16x16x32_f16(
              af[kk][m], bflo[kk][n], acc[4 + m][n], 0, 0, 0);
    __builtin_amdgcn_s_setprio(0);
    __builtin_amdgcn_s_barrier();
    // ---------------- P4: (rh1, nhi) ----------------
    if (t + 2 < NT) { STAGE(0, t + 2); STAGE(1, t + 2); }
    __builtin_amdgcn_sched_barrier(0);
    __builtin_amdgcn_s_barrier();
    __builtin_amdgcn_s_setprio(1);
#pragma unroll
    for (int kk = 0; kk < 2; ++kk)
#pragma unroll
      for (int m = 0; m < 4; ++m)
#pragma unroll
        for (int n = 0; n < 2; ++n)
          acc[4 + m][2 + n] = __builtin_amdgcn_mfma_f32_16x16x32_f16(
              af[kk][m], bfhi[kk][n], acc[4 + m][2 + n], 0, 0, 0);
    __builtin_amdgcn_s_setprio(0);
    if (t + 2 < NT)
      asm volatile("s_waitcnt vmcnt(6)" ::: "memory");
    else
      asm volatile("s_waitcnt vmcnt(0)" ::: "memory");
    __builtin_amdgcn_sched_barrier(0);
    __builtin_amdgcn_s_barrier();
  }

  // ---- fused epilogue: out = S(256x[8A x 32t]) x C3(32x64) + bias ----
  h8 bfe[4];
#pragma unroll
  for (int n = 0; n < 4; ++n)
#pragma unroll
    for (int j = 0; j < 8; ++j)
      bfe[n][j] = (_Float16)c3[(kh * 8 + j) * 64 + n * 16 + lr];
  __syncthreads();
  {
    const int wmo = (w >> 2) << 7;
    const int wno = (w & 3) << 6;
#pragma unroll
    for (int m = 0; m < 8; ++m) {
      const int Rb = wmo + m * 16 + kh * 4;
#pragma unroll
      for (int n = 0; n < 4; ++n) {
        const int cc = wno + n * 16 + lr;
#pragma unroll
        for (int q = 0; q < 4; ++q) {
          const int R = Rb + q;
          *(_Float16*)(lds + R * 512 +
                       ((((cc >> 3) ^ (R & 7)) << 4) | ((cc & 7) << 1))) =
              (_Float16)acc[m][n][q];
        }
      }
    }
  }
  __syncthreads();
  const int r32 = w << 5;
#pragma unroll
  for (int a = 0; a < 8; ++a) {
    f32x4 bs[4];
#pragma unroll
    for (int n = 0; n < 4; ++n)
      bs[n] = *(const f32x4*)&bias[(bn * 8 + a) * 64 + n * 16 + kh * 4];
#pragma unroll
    for (int mi = 0; mi < 2; ++mi) {
      const int rr = r32 + mi * 16 + lr;
      h8 afv = *(const h8*)(lds + rr * 512 +
                            ((((a * 4 + kh) ^ (rr & 7)) << 4)));
      const size_t orow = (size_t)(bm * 256 + r32 + mi * 16 + lr);
#pragma unroll
      for (int n = 0; n < 4; ++n) {
        f32x4 d = __builtin_amdgcn_mfma_f32_16x16x32_f16(bfe[n], afv, bs[n],
                                                         0, 0, 0);
        *(f32x4*)&out[orow * 4096 + (bn * 8 + a) * 64 + n * 16 + kh * 4] = d;
      }
    }
  }
}

extern "C" void kernel_launch(void* const* d_in, const int* in_sizes, int n_in,
                              void* d_out, int out_size, void* d_ws,
                              size_t ws_size, hipStream_t stream) {
  (void)in_sizes; (void)n_in; (void)out_size; (void)ws_size;
  const float* x     = (const float*)d_in[0];
  const float* core0 = (const float*)d_in[1];  // (1,64,32)
  const float* core1 = (const float*)d_in[2];  // (32,64,1024)
  const float* core2 = (const float*)d_in[3];  // (1024,64,32)
  const float* core3 = (const float*)d_in[4];  // (32,64,1)
  const float* bias  = (const float*)d_in[5];  // (4096,)
  float* out = (float*)d_out;

  char* ws = (char*)d_ws;
  _Float16* s1h = (_Float16*)ws;                        // 8192x2048 fp16
  _Float16* s2h = (_Float16*)(ws + 33554432);           // 8192x1024 fp16
  _Float16* W1t = (_Float16*)(ws + 50331648);           // 1024x2048 fp16
  _Float16* W2t = (_Float16*)(ws + 54525952);           // 2048x1024 fp16

  transpose_cast2<<<dim3(32, 16, 2), 256, 0, stream>>>(core1, W1t, core2, W2t);
  stage2<<<BATCH / 4, 512, 0, stream>>>(x, core0, s1h);
  gemm_pipe<2048, 1024, 64><<<256, 512, 0, stream>>>(s1h, W1t, s2h);
  gemm2_8ph<1024, 32><<<256, 512, 0, stream>>>(s2h, W2t, core3, bias, out);
}

// Round 11
// 148.199 us; speedup vs baseline: 1.0716x; 1.0716x over previous
//
#include <hip/hip_runtime.h>
#include <hip/hip_bf16.h>

// TT-Linear: out = (((x~(B,64,64) x C0) x C1) x C2) x C3 + bias
// Pipeline: transpose_cast2 -> stage2(dot2) -> gemm_pipe (gemm1) -> gemm2_8ph
// gemm2_8ph: 8-phase 256x256 BK=64 (r8, best) + operand-swapped epilogue.
// Round 11: clean revert to the round-9 kernel (best measured: ~149 us).

typedef _Float16 h2 __attribute__((ext_vector_type(2)));
typedef _Float16 h4 __attribute__((ext_vector_type(4)));
typedef _Float16 h8 __attribute__((ext_vector_type(8)));
typedef float f32x4 __attribute__((ext_vector_type(4)));

#define BATCH 8192

#if __has_builtin(__builtin_amdgcn_fdot2)
#define FDOT2(a, b, c) __builtin_amdgcn_fdot2((a), (b), (c), false)
#else
__device__ __forceinline__ float FDOT2(h2 a, h2 b, float c) {
  return c + (float)a[0] * (float)b[0] + (float)a[1] * (float)b[1];
}
#endif

__device__ __forceinline__ void gld_lds16(const void* g, void* l) {
  __builtin_amdgcn_global_load_lds(
      (__attribute__((address_space(1))) void*)(g),
      (__attribute__((address_space(3))) void*)(l), 16, 0, 0);
}

// Both weight transposes in one launch. grid (32,16,2).
__global__ __launch_bounds__(256) void transpose_cast2(
    const float* __restrict__ c1, _Float16* __restrict__ W1t,
    const float* __restrict__ c2, _Float16* __restrict__ W2t) {
  __shared__ float t[64][65];
  const int which = blockIdx.z;
  const float* src = which ? c2 : c1;
  _Float16* dst = which ? W2t : W1t;
  const int K = which ? 1024 : 2048, U = which ? 2048 : 1024;
  const int k0 = (which ? blockIdx.y : blockIdx.x) * 64;
  const int u0 = (which ? blockIdx.x : blockIdx.y) * 64;
  const int tx = threadIdx.x & 63, ty = threadIdx.x >> 6;
  for (int i = ty; i < 64; i += 4) {
    const int k = k0 + i;
    const int sr = which ? k : ((k & 31) * 64 + (k >> 5));
    t[i][tx] = src[(size_t)sr * U + u0 + tx];
  }
  __syncthreads();
  for (int i = ty; i < 64; i += 4) {
    dst[(size_t)(u0 + i) * K + k0 + tx] = (_Float16)t[tx][i];
  }
}

// stage2 (dot2): s1[b, d*32+r] = sum_c x[b,c*64+d]*C0[c*32+r], fp16 out.
// x staged as c-pairs: xh2[row][cp][d][2] = (x[2cp,d], x[2cp+1,d]) halves;
// C0 as c0h[cp][r][2]. Inner: 32 v_dot2_f32_f16 + 3 ds_read_b128 per cp.
__global__ __launch_bounds__(256) void stage2(const float* __restrict__ x,
                                              const float* __restrict__ c0,
                                              _Float16* __restrict__ s1) {
  __shared__ _Float16 xh2[4 * 4096];  // 32 KB
  __shared__ _Float16 c0h[2048];      // 4 KB
  const int b0 = blockIdx.x * 4;
  const int tid = threadIdx.x;

  {
#pragma unroll
    for (int i = 0; i < 8; ++i) {
      const int flat = tid + 256 * i;  // pair-slot: 4 rows x 512
      const int row = flat >> 9;
      const int s = flat & 511;
      const int cp = s >> 4, d0 = (s & 15) * 4;
      const float* gb = x + (size_t)(b0 + row) * 4096 + cp * 128 + d0;
      float4 fa = *(const float4*)gb;         // c = 2cp
      float4 fb = *(const float4*)(gb + 64);  // c = 2cp+1
      h8 o = {(_Float16)fa.x, (_Float16)fb.x, (_Float16)fa.y, (_Float16)fb.y,
              (_Float16)fa.z, (_Float16)fb.z, (_Float16)fa.w, (_Float16)fb.w};
      *(h8*)&xh2[row * 4096 + cp * 128 + d0 * 2] = o;
    }
#pragma unroll
    for (int i = 0; i < 4; ++i) {
      const int p = tid + 256 * i;  // 1024 C0 pairs
      const int cp = p >> 5, r = p & 31;
      h2 o = {(_Float16)c0[cp * 64 + r], (_Float16)c0[cp * 64 + 32 + r]};
      *(h2*)&c0h[cp * 64 + r * 2] = o;
    }
  }
  __syncthreads();

  const int row = tid >> 6, t6 = tid & 63;
  const int d0 = (t6 >> 3) * 8;  // broadcast reads
  const int r0 = (t6 & 7) * 4;   // contiguous stores
  const _Float16* xrow = xh2 + row * 4096;

  float acc[8][4] = {};
  for (int cp = 0; cp < 32; ++cp) {
    h8 xa = *(const h8*)&xrow[cp * 128 + d0 * 2];      // d0..d0+3 pairs
    h8 xb = *(const h8*)&xrow[cp * 128 + d0 * 2 + 8];  // d0+4..d0+7 pairs
    h8 wv = *(const h8*)&c0h[cp * 64 + r0 * 2];        // r0..r0+3 pairs
#pragma unroll
    for (int i = 0; i < 4; ++i) {
      h2 xi = {xa[2 * i], xa[2 * i + 1]};
      h2 xj = {xb[2 * i], xb[2 * i + 1]};
#pragma unroll
      for (int j = 0; j < 4; ++j) {
        h2 wj = {wv[2 * j], wv[2 * j + 1]};
        acc[i][j] = FDOT2(xi, wj, acc[i][j]);
        acc[i + 4][j] = FDOT2(xj, wj, acc[i + 4][j]);
      }
    }
  }

  _Float16* s1row = s1 + (size_t)(b0 + row) * 2048;
#pragma unroll
  for (int i = 0; i < 8; ++i) {
    h4 o = {(_Float16)acc[i][0], (_Float16)acc[i][1], (_Float16)acc[i][2],
            (_Float16)acc[i][3]};
    *(h4*)&s1row[(d0 + i) * 32 + r0] = o;
  }
}

// gemm1 (r5 structure, best measured): BM=128, BN=256, BK=64, 512 threads,
// 3 LDS buffers, counted vmcnt(6), 2-phase fine interleave per K-tile.
template <int K, int CN>
__global__ __launch_bounds__(512, 2) void gemm_pipe(
    const _Float16* __restrict__ A, const _Float16* __restrict__ Bt,
    _Float16* __restrict__ C) {
  __shared__ __align__(16) char lds[3 * 49152];
  constexpr int NT = K / 64;
  const int bm = blockIdx.x, bn = blockIdx.y;
  const int tid = threadIdx.x;
  const int w = tid >> 6, lane = tid & 63;
  const int lr = lane & 15, kh = lane >> 4;
  const int wmo = (w >> 2) << 6, wno = (w & 3) << 6;

  f32x4 acc[4][4] = {};

  const int sr = tid >> 3;
  const int sc = ((tid & 7) ^ (sr & 7)) << 4;
  const char* gA = (const char*)(A + (size_t)(bm * 128 + sr) * K) + sc;
  const char* gB = (const char*)(Bt + (size_t)(bn * 256 + sr) * K) + sc;
  const size_t rk = (size_t)K * 128;
  char* lw = lds + (w << 10);

  auto STAGE_A = [&](int t) {
    char* b_ = lw + (t % 3) * 49152;
    const char* ga = gA + (size_t)t * 128;
    gld_lds16(ga, b_);
    gld_lds16(ga + rk, b_ + 8192);
    gld_lds16(gB + (size_t)t * 128, b_ + 16384);
  };
  auto STAGE_B = [&](int t) {
    char* b_ = lw + (t % 3) * 49152;
    const char* gb = gB + (size_t)t * 128;
    gld_lds16(gb + rk, b_ + 24576);
    gld_lds16(gb + 2 * rk, b_ + 32768);
    gld_lds16(gb + 3 * rk, b_ + 40960);
  };

  auto KTILE = [&](int t, bool last) {
    if (last)
      asm volatile("s_waitcnt vmcnt(0)" ::: "memory");
    else
      asm volatile("s_waitcnt vmcnt(6)" ::: "memory");
    __builtin_amdgcn_s_barrier();
    __builtin_amdgcn_sched_barrier(0);
    const char* bufA = lds + (t % 3) * 49152;
    const char* bufB = bufA + 16384;
    h8 af[2][4], bf[2][4];
#pragma unroll
    for (int kk = 0; kk < 2; ++kk) {
#pragma unroll
      for (int m = 0; m < 4; ++m) {
        const int R = wmo + m * 16 + lr;
        af[kk][m] = *(const h8*)(bufA + R * 128 +
                                 ((((kk << 2) + kh) ^ (R & 7)) << 4));
      }
#pragma unroll
      for (int n = 0; n < 2; ++n) {
        const int R = wno + n * 16 + lr;
        bf[kk][n] = *(const h8*)(bufB + R * 128 +
                                 ((((kk << 2) + kh) ^ (R & 7)) << 4));
      }
    }
    if (t + 2 < NT) STAGE_A(t + 2);
    asm volatile("s_waitcnt lgkmcnt(0)" ::: "memory");
    __builtin_amdgcn_sched_barrier(0);
    __builtin_amdgcn_s_setprio(1);
#pragma unroll
    for (int kk = 0; kk < 2; ++kk)
#pragma unroll
      for (int m = 0; m < 4; ++m)
#pragma unroll
        for (int n = 0; n < 2; ++n)
          acc[m][n] = __builtin_amdgcn_mfma_f32_16x16x32_f16(
              af[kk][m], bf[kk][n], acc[m][n], 0, 0, 0);
    __builtin_amdgcn_s_setprio(0);
    __builtin_amdgcn_s_barrier();
    __builtin_amdgcn_sched_barrier(0);
#pragma unroll
    for (int kk = 0; kk < 2; ++kk)
#pragma unroll
      for (int n = 2; n < 4; ++n) {
        const int R = wno + n * 16 + lr;
        bf[kk][n] = *(const h8*)(bufB + R * 128 +
                                 ((((kk << 2) + kh) ^ (R & 7)) << 4));
      }
    if (t + 2 < NT) STAGE_B(t + 2);
    asm volatile("s_waitcnt lgkmcnt(0)" ::: "memory");
    __builtin_amdgcn_sched_barrier(0);
    __builtin_amdgcn_s_setprio(1);
#pragma unroll
    for (int kk = 0; kk < 2; ++kk)
#pragma unroll
      for (int m = 0; m < 4; ++m)
#pragma unroll
        for (int n = 2; n < 4; ++n)
          acc[m][n] = __builtin_amdgcn_mfma_f32_16x16x32_f16(
              af[kk][m], bf[kk][n], acc[m][n], 0, 0, 0);
    __builtin_amdgcn_s_setprio(0);
  };

  STAGE_A(0); STAGE_B(0);
  STAGE_A(1); STAGE_B(1);
  for (int t = 0; t < NT - 1; ++t) KTILE(t, false);
  KTILE(NT - 1, true);

#pragma unroll
  for (int m = 0; m < 4; ++m) {
    const int r0 = bm * 128 + wmo + m * 16 + kh * 4;
#pragma unroll
    for (int n = 0; n < 4; ++n) {
      const int c0 = bn * 256 + wno + n * 16 + lr;
#pragma unroll
      for (int q = 0; q < 4; ++q)
        C[(size_t)(r0 + q) * CN + c0] = (_Float16)acc[m][n][q];
    }
  }
}

// gemm2, 8-phase (r8 structure) + operand-swapped epilogue.
template <int K>
__global__ __launch_bounds__(512, 2) void gemm2_8ph(
    const _Float16* __restrict__ A, const _Float16* __restrict__ Bt,
    const float* __restrict__ c3, const float* __restrict__ bias,
    float* __restrict__ out) {
  __shared__ __align__(16) char lds[131072];
  constexpr int NT = K / 64;
  const int bm = blockIdx.x, bn = blockIdx.y;
  const int tid = threadIdx.x;
  const int w = tid >> 6, lane = tid & 63;
  const int lr = lane & 15, kh = lane >> 4;
  const int l7 = lr & 7;

  f32x4 acc[8][4] = {};

  const int sr = tid >> 3;
  const int sc = ((tid & 7) ^ (sr & 7)) << 4;
  const size_t rowK = (size_t)K * 2;
  const char* gA = (const char*)A + (size_t)(bm * 256 + sr) * rowK + sc;
  const char* gB = (const char*)Bt + (size_t)(bn * 256 + sr) * rowK + sc;
  char* lw = lds + (w << 10);

  auto STAGE = [&](int kind, int t) {
    char* d = lw + kind * 32768 + (t & 1) * 16384;
    const char* g = (kind < 2 ? gA : gB) + (size_t)(kind & 1) * 128 * rowK +
                    (size_t)t * 128;
    gld_lds16(g, d);
    gld_lds16(g + 64 * rowK, d + 8192);
  };

  const char* bufA0 = lds + (w >> 2) * 32768;
  const char* bufB0 = lds + 65536 + ((w & 3) >> 1) * 32768;
  const int bcol = (w & 1) * 64;

  h8 af[2][4], bflo[2][2], bfhi[2][2];

  STAGE(0, 0); STAGE(1, 0); STAGE(2, 0); STAGE(3, 0);
  STAGE(2, 1); STAGE(0, 1); STAGE(1, 1);
  asm volatile("s_waitcnt vmcnt(6)" ::: "memory");
  __builtin_amdgcn_sched_barrier(0);
  __builtin_amdgcn_s_barrier();

  for (int t = 0; t < NT; ++t) {
    const char* bA = bufA0 + (t & 1) * 16384;
    const char* bB = bufB0 + (t & 1) * 16384;
    // ---------------- P1: (rh0, nlo) ----------------
#pragma unroll
    for (int kk = 0; kk < 2; ++kk) {
#pragma unroll
      for (int m = 0; m < 4; ++m)
        af[kk][m] = *(const h8*)(bA + (m * 16 + lr) * 128 +
                                 ((((kk << 2) + kh) ^ l7) << 4));
#pragma unroll
      for (int n = 0; n < 2; ++n)
        bflo[kk][n] = *(const h8*)(bB + (bcol + n * 16 + lr) * 128 +
                                   ((((kk << 2) + kh) ^ l7) << 4));
    }
    if (t + 1 < NT) STAGE(3, t + 1);
    __builtin_amdgcn_sched_barrier(0);
    __builtin_amdgcn_s_barrier();
    asm volatile("s_waitcnt lgkmcnt(0)" ::: "memory");
    __builtin_amdgcn_sched_barrier(0);
    __builtin_amdgcn_s_setprio(1);
#pragma unroll
    for (int kk = 0; kk < 2; ++kk)
#pragma unroll
      for (int m = 0; m < 4; ++m)
#pragma unroll
        for (int n = 0; n < 2; ++n)
          acc[m][n] = __builtin_amdgcn_mfma_f32_16x16x32_f16(
              af[kk][m], bflo[kk][n], acc[m][n], 0, 0, 0);
    __builtin_amdgcn_s_setprio(0);
    __builtin_amdgcn_s_barrier();
    // ---------------- P2: (rh0, nhi) ----------------
#pragma unroll
    for (int kk = 0; kk < 2; ++kk)
#pragma unroll
      for (int n = 0; n < 2; ++n)
        bfhi[kk][n] = *(const h8*)(bB + (bcol + 32 + n * 16 + lr) * 128 +
                                   ((((kk << 2) + kh) ^ l7) << 4));
    if (t + 2 < NT) STAGE(2, t + 2);
    __builtin_amdgcn_sched_barrier(0);
    __builtin_amdgcn_s_barrier();
    asm volatile("s_waitcnt lgkmcnt(0)" ::: "memory");
    __builtin_amdgcn_sched_barrier(0);
    __builtin_amdgcn_s_setprio(1);
#pragma unroll
    for (int kk = 0; kk < 2; ++kk)
#pragma unroll
      for (int m = 0; m < 4; ++m)
#pragma unroll
        for (int n = 0; n < 2; ++n)
          acc[m][2 + n] = __builtin_amdgcn_mfma_f32_16x16x32_f16(
              af[kk][m], bfhi[kk][n], acc[m][2 + n], 0, 0, 0);
    __builtin_amdgcn_s_setprio(0);
    __builtin_amdgcn_s_barrier();
    // ---------------- P3: (rh1, nlo) ----------------
#pragma unroll
    for (int kk = 0; kk < 2; ++kk)
#pragma unroll
      for (int m = 0; m < 4; ++m)
        af[kk][m] = *(const h8*)(bA + (64 + m * 16 + lr) * 128 +
                                 ((((kk << 2) + kh) ^ l7) << 4));
    __builtin_amdgcn_sched_barrier(0);
    __builtin_amdgcn_s_barrier();
    asm volatile("s_waitcnt lgkmcnt(0)" ::: "memory");
    __builtin_amdgcn_sched_barrier(0);
    __builtin_amdgcn_s_setprio(1);
#pragma unroll
    for (int kk = 0; kk < 2; ++kk)
#pragma unroll
      for (int m = 0; m < 4; ++m)
#pragma unroll
        for (int n = 0; n < 2; ++n)
          acc[4 + m][n] = __builtin_amdgcn_mfma_f32_16x16x32_f16(
              af[kk][m], bflo[kk][n], acc[4 + m][n], 0, 0, 0);
    __builtin_amdgcn_s_setprio(0);
    __builtin_amdgcn_s_barrier();
    // ---------------- P4: (rh1, nhi) ----------------
    if (t + 2 < NT) { STAGE(0, t + 2); STAGE(1, t + 2); }
    __builtin_amdgcn_sched_barrier(0);
    __builtin_amdgcn_s_barrier();
    __builtin_amdgcn_s_setprio(1);
#pragma unroll
    for (int kk = 0; kk < 2; ++kk)
#pragma unroll
      for (int m = 0; m < 4; ++m)
#pragma unroll
        for (int n = 0; n < 2; ++n)
          acc[4 + m][2 + n] = __builtin_amdgcn_mfma_f32_16x16x32_f16(
              af[kk][m], bfhi[kk][n], acc[4 + m][2 + n], 0, 0, 0);
    __builtin_amdgcn_s_setprio(0);
    if (t + 2 < NT)
      asm volatile("s_waitcnt vmcnt(6)" ::: "memory");
    else
      asm volatile("s_waitcnt vmcnt(0)" ::: "memory");
    __builtin_amdgcn_sched_barrier(0);
    __builtin_amdgcn_s_barrier();
  }

  // ---- fused epilogue: out = S(256x[8A x 32t]) x C3(32x64) + bias ----
  // Operand-swapped: d = mfma(C3frag_as_A, Sfrag_as_B, bias_seed) puts
  // out-COLUMNS in the register dim => f32x4 stores.
  h8 bfe[4];
#pragma unroll
  for (int n = 0; n < 4; ++n)
#pragma unroll
    for (int j = 0; j < 8; ++j)
      bfe[n][j] = (_Float16)c3[(kh * 8 + j) * 64 + n * 16 + lr];
  __syncthreads();  // all slot reads done before S overwrite
  // S[256][256] fp16, 512B rows, chunk^(row&7) swizzle
  {
    const int wmo = (w >> 2) << 7;
    const int wno = (w & 3) << 6;
#pragma unroll
    for (int m = 0; m < 8; ++m) {
      const int Rb = wmo + m * 16 + kh * 4;
#pragma unroll
      for (int n = 0; n < 4; ++n) {
        const int cc = wno + n * 16 + lr;
#pragma unroll
        for (int q = 0; q < 4; ++q) {
          const int R = Rb + q;
          *(_Float16*)(lds + R * 512 +
                       ((((cc >> 3) ^ (R & 7)) << 4) | ((cc & 7) << 1))) =
              (_Float16)acc[m][n][q];
        }
      }
    }
  }
  __syncthreads();
  // wave w owns output rows [w*32, w*32+32)
  const int r32 = w << 5;
#pragma unroll
  for (int a = 0; a < 8; ++a) {
    f32x4 bs[4];
#pragma unroll
    for (int n = 0; n < 4; ++n)
      bs[n] = *(const f32x4*)&bias[(bn * 8 + a) * 64 + n * 16 + kh * 4];
#pragma unroll
    for (int mi = 0; mi < 2; ++mi) {
      const int rr = r32 + mi * 16 + lr;
      h8 afv = *(const h8*)(lds + rr * 512 +
                            ((((a * 4 + kh) ^ (rr & 7)) << 4)));
      const size_t orow = (size_t)(bm * 256 + r32 + mi * 16 + lr);
#pragma unroll
      for (int n = 0; n < 4; ++n) {
        f32x4 d = __builtin_amdgcn_mfma_f32_16x16x32_f16(bfe[n], afv, bs[n],
                                                         0, 0, 0);
        *(f32x4*)&out[orow * 4096 + (bn * 8 + a) * 64 + n * 16 + kh * 4] = d;
      }
    }
  }
}

extern "C" void kernel_launch(void* const* d_in, const int* in_sizes, int n_in,
                              void* d_out, int out_size, void* d_ws,
                              size_t ws_size, hipStream_t stream) {
  (void)in_sizes; (void)n_in; (void)out_size; (void)ws_size;
  const float* x     = (const float*)d_in[0];
  const float* core0 = (const float*)d_in[1];  // (1,64,32)
  const float* core1 = (const float*)d_in[2];  // (32,64,1024)
  const float* core2 = (const float*)d_in[3];  // (1024,64,32)
  const float* core3 = (const float*)d_in[4];  // (32,64,1)
  const float* bias  = (const float*)d_in[5];  // (4096,)
  float* out = (float*)d_out;

  char* ws = (char*)d_ws;
  _Float16* s1h = (_Float16*)ws;                        // 8192x2048 fp16
  _Float16* s2h = (_Float16*)(ws + 33554432);           // 8192x1024 fp16
  _Float16* W1t = (_Float16*)(ws + 50331648);           // 1024x2048 fp16
  _Float16* W2t = (_Float16*)(ws + 54525952);           // 2048x1024 fp16

  transpose_cast2<<<dim3(32, 16, 2), 256, 0, stream>>>(core1, W1t, core2, W2t);
  stage2<<<BATCH / 4, 256, 0, stream>>>(x, core0, s1h);
  gemm_pipe<2048, 1024><<<dim3(BATCH / 128, 4), 512, 0, stream>>>(s1h, W1t, s2h);
  gemm2_8ph<1024><<<dim3(BATCH / 256, 2048 / 256), 512, 0, stream>>>(
      s2h, W2t, core3, bias, out);
}